// Round 10
// baseline (509.202 us; speedup 1.0000x reference)
//
#include <hip/hip_runtime.h>
#include <hip/hip_cooperative_groups.h>

namespace cg = cooperative_groups;

#define LBL 32
#define NPIX (736 * 736)   // 541696
#define NQ (NPIX / 4)      // 135424 float4-quads per batch
#define GPB 128            // blocks per batch
#define QPB (NQ / GPB)     // 1058 quads per block (exact)
#define BATCH 8
#define DELTA_AGG 0.5f
#define DELTA_DIS 1.5f
#define REG_W 0.001f

// ws layout (float indices), ~0.9 MB — all slots plain-stored before read:
//  partA: [PA_BASE, +8*128*192)  block-major: cnt_k[32] ([0]=saw-lbl0), sum[128], cnt_a[32]
//  red:   [RED_BASE, +8*256)     per batch RAW totals (same elem order)
//  partV: [PV_BASE, +8*128*32)   block-major: val[32]
#define PA_BASE 0
#define RED_BASE (BATCH * GPB * 192)       // 196608
#define PV_BASE (RED_BASE + BATCH * 256)   // 198656
// end: PV_BASE + 8*128*32 = 231424 floats

__device__ __forceinline__ unsigned int f2bf(float f) {  // RTNE
  unsigned int u = __float_as_uint(f);
  unsigned int r = u + 0x7FFFu + ((u >> 16) & 1u);
  return r >> 16;
}
__device__ __forceinline__ float bfl(unsigned int w) {
  return __uint_as_float(w << 16);
}
__device__ __forceinline__ float bfh(unsigned int w) {
  return __uint_as_float(w & 0xFFFF0000u);
}

__global__ __launch_bounds__(256, 4) void kFused(
    const float* __restrict__ emb, const int* __restrict__ inst,
    const float* __restrict__ kern, const float* __restrict__ mask,
    float* __restrict__ ws, float* __restrict__ out) {
  const int b = blockIdx.y;
  const int g = blockIdx.x;
  const int t = threadIdx.x;

  // LDS: 33856 + 4232 + 128 + 512 + 128 + 128 + 512 + 512 + 128 = 40136 B
  __shared__ unsigned int eL[8][QPB];   // [j*2+w][qb] bf16-pair words
  __shared__ unsigned int labL[QPB];    // packed mask-only labels (4 px/word)
  __shared__ float s_cnt[LBL];          // kernel-region counts; [0]=saw-lbl0 flag
  __shared__ float s_sum[LBL * 4];
  __shared__ float s_cta[LBL];          // mask-only counts (cnt_a)
  __shared__ float s_val[LBL];
  __shared__ float s_mean[LBL * 4];
  __shared__ float red4[128];
  __shared__ float sv[LBL];

  if (t < LBL) { s_cnt[t] = 0.f; s_cta[t] = 0.f; }
  if (t < LBL * 4) s_sum[t] = 0.f;
  __syncthreads();

  const long base = (long)b * NPIX;
  const float* ebase = emb + (long)b * 4 * NPIX;
  const int4* ip = (const int4*)(inst + base);
  const float4* kp = (const float4*)(kern + base);
  const float4* mp = (const float4*)(mask + base);
  const float4* p0 = (const float4*)(ebase);
  const float4* p1 = (const float4*)(ebase + NPIX);
  const float4* p2 = (const float4*)(ebase + 2 * NPIX);
  const float4* p3 = (const float4*)(ebase + 3 * NPIX);

  const int qStart = g * QPB;
  bool has0 = false;

  // ---- P1: stream inputs once; histograms + LDS-cache emb/labels ----
  for (int r = 0; r < 5; ++r) {
    const int qb = r * 256 + t;
    if (qb >= QPB) break;  // r=4: only t<34
    const int qg = qStart + qb;
    const int4 iv = ip[qg];
    const float4 kv = kp[qg];
    const float4 mv = mp[qg];
    const float4 e0 = p0[qg], e1 = p1[qg], e2 = p2[qg], e3 = p3[qg];

    const int labs[4] = {iv.x, iv.y, iv.z, iv.w};
    const float ks[4] = {kv.x, kv.y, kv.z, kv.w};
    const float ms[4] = {mv.x, mv.y, mv.z, mv.w};
    const float c0[4] = {e0.x, e0.y, e0.z, e0.w};
    const float c1[4] = {e1.x, e1.y, e1.z, e1.w};
    const float c2[4] = {e2.x, e2.y, e2.z, e2.w};
    const float c3[4] = {e3.x, e3.y, e3.z, e3.w};

    unsigned int labw = 0;
#pragma unroll
    for (int j = 0; j < 4; j++) {
      const bool m = ms[j] > 0.5f;
      const int li = m ? labs[j] : 0;
      const int lk = (m && ks[j] > 0.5f) ? labs[j] : 0;
      labw |= ((unsigned int)li) << (8 * j);
      eL[j * 2 + 0][qb] = f2bf(c0[j]) | (f2bf(c1[j]) << 16);
      eL[j * 2 + 1][qb] = f2bf(c2[j]) | (f2bf(c3[j]) << 16);
      if (li > 0) atomicAdd(&s_cta[li], 1.0f);
      if (lk > 0) {
        atomicAdd(&s_cnt[lk], 1.0f);
        atomicAdd(&s_sum[lk * 4 + 0], c0[j]);
        atomicAdd(&s_sum[lk * 4 + 1], c1[j]);
        atomicAdd(&s_sum[lk * 4 + 2], c2[j]);
        atomicAdd(&s_sum[lk * 4 + 3], c3[j]);
      } else {
        has0 = true;
      }
    }
    labL[qb] = labw;
  }
  if (has0) s_cnt[0] = 1.0f;  // benign race
  __syncthreads();
  {
    float* po = ws + PA_BASE + ((size_t)(b * GPB + g)) * 192;
    if (t < 192)
      po[t] = (t < 32) ? s_cnt[t] : (t < 160 ? s_sum[t - 32] : s_cta[t - 160]);
  }
  cg::this_grid().sync();

  // ---- P2a: 8 blocks (g==0) reduce partials -> RED raw totals ----
  if (g == 0 && t < 192) {
    const float* pa = ws + PA_BASE + (size_t)b * GPB * 192 + t;
    float s = 0.f;
    for (int k = 0; k < GPB; k++) s += pa[(size_t)k * 192];
    ws[RED_BASE + b * 256 + t] = s;
  }
  cg::this_grid().sync();

  // ---- P2b: distances from LDS-resident bf16 emb ----
  const float* rd = ws + RED_BASE + b * 256;
  if (t < LBL * 4) {
    const int l = t >> 2;
    s_mean[t] = (l == 0) ? 0.f : rd[32 + t] / fmaxf(rd[l], 1.0f);
  }
  if (t < LBL) s_val[t] = 0.f;
  __syncthreads();

  for (int r = 0; r < 5; ++r) {
    const int qb = r * 256 + t;
    if (qb >= QPB) break;
    const unsigned int labw = labL[qb];
#pragma unroll
    for (int j = 0; j < 4; j++) {
      const int li = (labw >> (8 * j)) & 0xFF;
      if (li > 0) {
        const unsigned int w0 = eL[j * 2 + 0][qb];
        const unsigned int w1 = eL[j * 2 + 1][qb];
        const float d0 = bfl(w0) - s_mean[li * 4 + 0];
        const float d1 = bfh(w0) - s_mean[li * 4 + 1];
        const float d2 = bfl(w1) - s_mean[li * 4 + 2];
        const float d3 = bfh(w1) - s_mean[li * 4 + 3];
        const float sq = d0 * d0 + d1 * d1 + d2 * d2 + d3 * d3;
        const float dist = (sq > 0.f) ? sqrtf(sq) : 0.f;
        const float tt = fmaxf(dist - DELTA_AGG, 0.f);
        atomicAdd(&s_val[li], logf(fmaf(tt, tt, 1.0f)));
      }
    }
  }
  __syncthreads();
  if (t < 32) ws[PV_BASE + ((size_t)(b * GPB + g)) * 32 + t] = s_val[t];
  cg::this_grid().sync();

  // ---- P3: 8 blocks (g==0) reduce val partials + finalize ----
  if (g != 0) return;
  {
    const float* pv = ws + PV_BASE + (size_t)b * GPB * 32;
    if (t < 128) {
      const int c = t >> 5, col = t & 31;
      float s = 0.f;
      for (int k = c; k < GPB; k += 4) s += pv[(size_t)k * 32 + col];
      red4[t] = s;
    }
    __syncthreads();
    if (t < 32) sv[t] = red4[t] + red4[32 + t] + red4[64 + t] + red4[96 + t];
    __syncthreads();
  }

  if (t < 64) {  // wave 0 only
    const int lane = t;
    const float cntk = (lane < LBL) ? rd[lane] : 0.f;
    const float cnta = (lane < LBL) ? rd[160 + lane] : 0.f;
    const bool pres = (lane < LBL) && (cntk > 0.f);
    const unsigned long long bal_p = __ballot(pres);
    const int num_instance = __popcll(bal_p);
    const bool nz = pres && (lane > 0);
    const unsigned long long bal_nz = __ballot(nz);

    float agg = 0.f;
    if (nz) agg = sv[lane] / fmaxf(cnta, 1.0f);

    float reg = 0.f;
    if (pres) {
      float sq = 0.f;
#pragma unroll
      for (int d = 0; d < 4; d++) sq += s_mean[lane * 4 + d] * s_mean[lane * 4 + d];
      const float nrm = (sq > 0.f) ? sqrtf(sq) : 0.f;
      reg = logf(nrm + 1.0f);
    }

    float dis = 0.f, npair = 0.f;
    for (int pi = lane; pi < LBL * LBL; pi += 64) {
      const int i = pi >> 5, j = pi & 31;
      if (i != j && ((bal_nz >> i) & 1ull) && ((bal_nz >> j) & 1ull)) {
        float sq = 0.f;
#pragma unroll
        for (int d = 0; d < 4; d++) {
          const float df = s_mean[i * 4 + d] - s_mean[j * 4 + d];
          sq += df * df;
        }
        const float pdist = (sq > 0.f) ? sqrtf(sq) : 0.f;
        const float tt = fmaxf(2.0f * DELTA_DIS - pdist, 0.f);
        dis += logf(fmaf(tt, tt, 1.0f));
        npair += 1.0f;
      }
    }

#pragma unroll
    for (int o = 32; o > 0; o >>= 1) {
      agg += __shfl_down(agg, o);
      reg += __shfl_down(reg, o);
      dis += __shfl_down(dis, o);
      npair += __shfl_down(npair, o);
    }

    if (lane == 0) {
      const float l_agg = agg / fmaxf((float)(num_instance - 1), 1.0f);
      const float l_dis = (num_instance > 2) ? dis / fmaxf(npair, 1.0f) : 0.f;
      const float l_reg = reg / fmaxf((float)num_instance, 1.0f) * REG_W;
      const float loss = l_agg + l_dis + l_reg;
      out[b] = (num_instance <= 1) ? 0.f : loss;
    }
  }
}

extern "C" void kernel_launch(void* const* d_in, const int* in_sizes, int n_in,
                              void* d_out, int out_size, void* d_ws,
                              size_t ws_size, hipStream_t stream) {
  const float* emb = (const float*)d_in[0];
  const int* instance = (const int*)d_in[1];
  const float* kern = (const float*)d_in[2];
  const float* mask = (const float*)d_in[3];
  float* out = (float*)d_out;
  float* ws = (float*)d_ws;

  void* args[] = {(void*)&emb, (void*)&instance, (void*)&kern,
                  (void*)&mask, (void*)&ws, (void*)&out};
  // 1024 blocks = 4/CU exactly (launch_bounds(256,4), LDS ~40.1 KB <= 160/4 KB)
  hipLaunchCooperativeKernel(kFused, dim3(GPB, BATCH), dim3(256), args, 0,
                             stream);
}

// Round 11
// 182.445 us; speedup vs baseline: 2.7910x; 2.7910x over previous
//
#include <hip/hip_runtime.h>

#define LBL 32
#define NPIX (736 * 736)   // 541696
#define NQ (NPIX / 4)      // 135424 float4-quads per batch
#define QPB 512            // quads per block (2 per thread)
#define NBA 265            // ceil(NQ/QPB); block 264: only first quad-set valid
#define BATCH 8
#define DELTA_AGG 0.5f
#define DELTA_DIS 1.5f
#define REG_W 0.001f

// ws layout (float indices), ~41 MB — all slots plain-stored before read:
//  ce:    [0, +8*NPIX*2)           bf16 e[4] per px, 32 B per quad (2x uint4)
//  lab:   [LAB_BASE, +8*NQ)        packed mask-only labels, 4 px per uint32
//  partA: [PA_BASE, +8*NBA*192)    block-major: cnt_k[32]([0]=flag), sum[128], cnt_a[32]
//  red:   [RED_BASE, +8*256)       per batch RAW totals, same elem order
//  partC: [PC_BASE, +8*NBA*32)     block-major: val[32]
#define CE_BASE 0
#define LAB_BASE (BATCH * NPIX * 2)             // 8667136
#define PA_BASE (LAB_BASE + BATCH * NQ)         // 9750528
#define RED_BASE (PA_BASE + BATCH * NBA * 192)  // 10157568
#define PC_BASE (RED_BASE + BATCH * 256)        // 10159616
// end: PC_BASE + 8*265*32 = 10227456 floats = 40.9 MB

__device__ __forceinline__ unsigned short f2bf(float f) {  // RTNE
  unsigned int u = __float_as_uint(f);
  unsigned int r = u + 0x7FFFu + ((u >> 16) & 1u);
  return (unsigned short)(r >> 16);
}
__device__ __forceinline__ float bfl(unsigned int w) {
  return __uint_as_float(w << 16);
}
__device__ __forceinline__ float bfh(unsigned int w) {
  return __uint_as_float(w & 0xFFFF0000u);
}

// ===== Pass A: histograms (cnt_k, sums, cnt_a) + bf16/label spill ===========
__global__ __launch_bounds__(256) void kA(
    const float* __restrict__ emb, const int* __restrict__ inst,
    const float* __restrict__ kern, const float* __restrict__ mask,
    float* __restrict__ ws) {
  const int b = blockIdx.y;
  const int t = threadIdx.x;
  __shared__ float s_cnt[LBL];   // [0] = "saw label 0" flag
  __shared__ float s_sum[LBL * 4];
  __shared__ float s_cta[LBL];   // mask-only counts (cnt_a)
  if (t < LBL) { s_cnt[t] = 0.f; s_cta[t] = 0.f; }
  if (t < LBL * 4) s_sum[t] = 0.f;
  __syncthreads();

  const long base = (long)b * NPIX;
  const float* ebase = emb + (long)b * 4 * NPIX;
  const int4* ip = (const int4*)(inst + base);
  const float4* kp = (const float4*)(kern + base);
  const float4* mp = (const float4*)(mask + base);
  const float4* p0 = (const float4*)(ebase);
  const float4* p1 = (const float4*)(ebase + NPIX);
  const float4* p2 = (const float4*)(ebase + 2 * NPIX);
  const float4* p3 = (const float4*)(ebase + 3 * NPIX);

  const int q0 = blockIdx.x * QPB + t;
  const int q1 = q0 + 256;
  const bool v1 = (q1 < NQ);  // block-uniform (false only for block 264)

  // issue ALL loads up front — max MLP
  const int4 iva = ip[q0];
  const float4 kva = kp[q0], mva = mp[q0];
  const float4 ea0 = p0[q0], ea1 = p1[q0], ea2 = p2[q0], ea3 = p3[q0];
  int4 ivb;
  float4 kvb, mvb, fb0, fb1, fb2, fb3;
  if (v1) {
    ivb = ip[q1]; kvb = kp[q1]; mvb = mp[q1];
    fb0 = p0[q1]; fb1 = p1[q1]; fb2 = p2[q1]; fb3 = p3[q1];
  }

  bool has0 = false;
  unsigned int* labp = (unsigned int*)(ws + LAB_BASE) + (size_t)b * NQ;
  uint4* cep = (uint4*)(ws + CE_BASE) + (size_t)b * NQ * 2;

  {
    const int labs[4] = {iva.x, iva.y, iva.z, iva.w};
    const float ks[4] = {kva.x, kva.y, kva.z, kva.w};
    const float ms[4] = {mva.x, mva.y, mva.z, mva.w};
    const float c0[4] = {ea0.x, ea0.y, ea0.z, ea0.w};
    const float c1[4] = {ea1.x, ea1.y, ea1.z, ea1.w};
    const float c2[4] = {ea2.x, ea2.y, ea2.z, ea2.w};
    const float c3[4] = {ea3.x, ea3.y, ea3.z, ea3.w};
    unsigned int labw = 0;
    union { unsigned short us[16]; uint4 v[2]; } pk;
#pragma unroll
    for (int j = 0; j < 4; j++) {
      const bool m = ms[j] > 0.5f;
      const int li = m ? labs[j] : 0;
      const int lk = (m && ks[j] > 0.5f) ? labs[j] : 0;
      labw |= ((unsigned int)li) << (8 * j);
      pk.us[j * 4 + 0] = f2bf(c0[j]);
      pk.us[j * 4 + 1] = f2bf(c1[j]);
      pk.us[j * 4 + 2] = f2bf(c2[j]);
      pk.us[j * 4 + 3] = f2bf(c3[j]);
      if (li > 0) atomicAdd(&s_cta[li], 1.0f);
      if (lk > 0) {
        atomicAdd(&s_cnt[lk], 1.0f);
        atomicAdd(&s_sum[lk * 4 + 0], c0[j]);
        atomicAdd(&s_sum[lk * 4 + 1], c1[j]);
        atomicAdd(&s_sum[lk * 4 + 2], c2[j]);
        atomicAdd(&s_sum[lk * 4 + 3], c3[j]);
      } else {
        has0 = true;
      }
    }
    labp[q0] = labw;
    cep[(size_t)q0 * 2] = pk.v[0];
    cep[(size_t)q0 * 2 + 1] = pk.v[1];
  }
  if (v1) {
    const int labs[4] = {ivb.x, ivb.y, ivb.z, ivb.w};
    const float ks[4] = {kvb.x, kvb.y, kvb.z, kvb.w};
    const float ms[4] = {mvb.x, mvb.y, mvb.z, mvb.w};
    const float c0[4] = {fb0.x, fb0.y, fb0.z, fb0.w};
    const float c1[4] = {fb1.x, fb1.y, fb1.z, fb1.w};
    const float c2[4] = {fb2.x, fb2.y, fb2.z, fb2.w};
    const float c3[4] = {fb3.x, fb3.y, fb3.z, fb3.w};
    unsigned int labw = 0;
    union { unsigned short us[16]; uint4 v[2]; } pk;
#pragma unroll
    for (int j = 0; j < 4; j++) {
      const bool m = ms[j] > 0.5f;
      const int li = m ? labs[j] : 0;
      const int lk = (m && ks[j] > 0.5f) ? labs[j] : 0;
      labw |= ((unsigned int)li) << (8 * j);
      pk.us[j * 4 + 0] = f2bf(c0[j]);
      pk.us[j * 4 + 1] = f2bf(c1[j]);
      pk.us[j * 4 + 2] = f2bf(c2[j]);
      pk.us[j * 4 + 3] = f2bf(c3[j]);
      if (li > 0) atomicAdd(&s_cta[li], 1.0f);
      if (lk > 0) {
        atomicAdd(&s_cnt[lk], 1.0f);
        atomicAdd(&s_sum[lk * 4 + 0], c0[j]);
        atomicAdd(&s_sum[lk * 4 + 1], c1[j]);
        atomicAdd(&s_sum[lk * 4 + 2], c2[j]);
        atomicAdd(&s_sum[lk * 4 + 3], c3[j]);
      } else {
        has0 = true;
      }
    }
    labp[q1] = labw;
    cep[(size_t)q1 * 2] = pk.v[0];
    cep[(size_t)q1 * 2 + 1] = pk.v[1];
  }

  if (has0) s_cnt[0] = 1.0f;  // benign race
  __syncthreads();
  // block-major coalesced partial store (no write amplification)
  float* po = ws + PA_BASE + ((size_t)b * NBA + blockIdx.x) * 192;
  if (t < 192)
    po[t] = (t < 32) ? s_cnt[t] : (t < 160 ? s_sum[t - 32] : s_cta[t - 160]);
}

// ===== Reduce A: one wave per (batch,elem) column, strided gather ===========
__global__ __launch_bounds__(256) void kB(float* __restrict__ ws) {
  const int b = blockIdx.y;
  const int col = blockIdx.x * 4 + (threadIdx.x >> 6);  // 48 blk x 4 waves = 192
  const int lane = threadIdx.x & 63;
  const float* pa = ws + PA_BASE + (size_t)b * NBA * 192 + col;
  float s = 0.f;
  for (int g = lane; g < NBA; g += 64) s += pa[(size_t)g * 192];
#pragma unroll
  for (int o = 32; o > 0; o >>= 1) s += __shfl_down(s, o);
  if (lane == 0) ws[RED_BASE + b * 256 + col] = s;  // raw totals
}

// ===== Pass C: aggregation val sums from the compact spill ==================
__global__ __launch_bounds__(256) void kC(float* __restrict__ ws) {
  const int b = blockIdx.y;
  const int t = threadIdx.x;
  __shared__ float s_mean[LBL * 4];
  __shared__ float s_val[LBL];
  const float* rd = ws + RED_BASE + b * 256;
  if (t < LBL * 4) {
    const int l = t >> 2;
    s_mean[t] = (l == 0) ? 0.f : rd[32 + t] / fmaxf(rd[l], 1.0f);
  }
  if (t < LBL) s_val[t] = 0.f;
  __syncthreads();

  const unsigned int* labp = (const unsigned int*)(ws + LAB_BASE) + (size_t)b * NQ;
  const uint4* cep = (const uint4*)(ws + CE_BASE) + (size_t)b * NQ * 2;
  const int q0 = blockIdx.x * QPB + t;
  const int q1 = q0 + 256;
  const bool v1 = (q1 < NQ);

  const unsigned int lwa = labp[q0];
  const uint4 ra0 = cep[(size_t)q0 * 2], ra1 = cep[(size_t)q0 * 2 + 1];
  unsigned int lwb = 0;
  uint4 rb0, rb1;
  if (v1) {
    lwb = labp[q1];
    rb0 = cep[(size_t)q1 * 2];
    rb1 = cep[(size_t)q1 * 2 + 1];
  }

  {
    const unsigned int wlo[4] = {ra0.x, ra0.z, ra1.x, ra1.z};
    const unsigned int whi[4] = {ra0.y, ra0.w, ra1.y, ra1.w};
#pragma unroll
    for (int j = 0; j < 4; j++) {
      const int li = (lwa >> (8 * j)) & 0xFF;
      if (li > 0) {
        const float d0 = bfl(wlo[j]) - s_mean[li * 4 + 0];
        const float d1 = bfh(wlo[j]) - s_mean[li * 4 + 1];
        const float d2 = bfl(whi[j]) - s_mean[li * 4 + 2];
        const float d3 = bfh(whi[j]) - s_mean[li * 4 + 3];
        const float sq = d0 * d0 + d1 * d1 + d2 * d2 + d3 * d3;
        const float dist = (sq > 0.f) ? sqrtf(sq) : 0.f;
        const float tt = fmaxf(dist - DELTA_AGG, 0.f);
        atomicAdd(&s_val[li], logf(fmaf(tt, tt, 1.0f)));
      }
    }
  }
  if (v1) {
    const unsigned int wlo[4] = {rb0.x, rb0.z, rb1.x, rb1.z};
    const unsigned int whi[4] = {rb0.y, rb0.w, rb1.y, rb1.w};
#pragma unroll
    for (int j = 0; j < 4; j++) {
      const int li = (lwb >> (8 * j)) & 0xFF;
      if (li > 0) {
        const float d0 = bfl(wlo[j]) - s_mean[li * 4 + 0];
        const float d1 = bfh(wlo[j]) - s_mean[li * 4 + 1];
        const float d2 = bfl(whi[j]) - s_mean[li * 4 + 2];
        const float d3 = bfh(whi[j]) - s_mean[li * 4 + 3];
        const float sq = d0 * d0 + d1 * d1 + d2 * d2 + d3 * d3;
        const float dist = (sq > 0.f) ? sqrtf(sq) : 0.f;
        const float tt = fmaxf(dist - DELTA_AGG, 0.f);
        atomicAdd(&s_val[li], logf(fmaf(tt, tt, 1.0f)));
      }
    }
  }
  __syncthreads();
  float* po = ws + PC_BASE + ((size_t)b * NBA + blockIdx.x) * 32;
  if (t < 32) po[t] = s_val[t];
}

// ===== Reduce C + finalize (one 1024-thread block per batch) ================
__global__ __launch_bounds__(1024) void kD(const float* __restrict__ ws,
                                           float* __restrict__ out) {
  const int b = blockIdx.x;
  const int t = threadIdx.x;
  const int col = t >> 5, sub = t & 31;  // 32 cols x 32 chunks
  const float* pc = ws + PC_BASE + (size_t)b * NBA * 32 + col;
  float s = 0.f;
  for (int g = sub; g < NBA; g += 32) s += pc[(size_t)g * 32];
  __shared__ float red[LBL][33];
  red[col][sub] = s;

  const float* rd = ws + RED_BASE + b * 256;
  __shared__ float sm[LBL * 4];
  __shared__ float scc[LBL];  // cnt_k
  __shared__ float sca[LBL];  // cnt_a
  if (t >= 512 && t < 640) {
    const int e = t - 512, l = e >> 2;
    sm[e] = (l == 0) ? 0.f : rd[32 + e] / fmaxf(rd[l], 1.0f);
  } else if (t >= 640 && t < 672) {
    scc[t - 640] = rd[t - 640];
  } else if (t >= 672 && t < 704) {
    sca[t - 672] = rd[160 + (t - 672)];
  }
  __syncthreads();
  __shared__ float sv[LBL];
  if (t < 32) {
    float v = 0.f;
#pragma unroll
    for (int k = 0; k < 32; k++) v += red[t][k];
    sv[t] = v;
  }
  __syncthreads();

  if (t < 64) {  // wave 0 only
    const int lane = t;
    const bool pres = (lane < LBL) && (scc[lane & 31] > 0.f);
    const unsigned long long bal_p = __ballot(pres);
    const int num_instance = __popcll(bal_p);
    const bool nz = pres && (lane > 0);
    const unsigned long long bal_nz = __ballot(nz);

    float agg = 0.f;
    if (nz) agg = sv[lane] / fmaxf(sca[lane], 1.0f);

    float reg = 0.f;
    if (pres) {
      float sq = 0.f;
#pragma unroll
      for (int d = 0; d < 4; d++) sq += sm[lane * 4 + d] * sm[lane * 4 + d];
      const float nrm = (sq > 0.f) ? sqrtf(sq) : 0.f;
      reg = logf(nrm + 1.0f);
    }

    float dis = 0.f, npair = 0.f;
    for (int pi = lane; pi < LBL * LBL; pi += 64) {
      const int i = pi >> 5, j = pi & 31;
      if (i != j && ((bal_nz >> i) & 1ull) && ((bal_nz >> j) & 1ull)) {
        float sq = 0.f;
#pragma unroll
        for (int d = 0; d < 4; d++) {
          const float df = sm[i * 4 + d] - sm[j * 4 + d];
          sq += df * df;
        }
        const float pdist = (sq > 0.f) ? sqrtf(sq) : 0.f;
        const float tt = fmaxf(2.0f * DELTA_DIS - pdist, 0.f);
        dis += logf(fmaf(tt, tt, 1.0f));
        npair += 1.0f;
      }
    }

#pragma unroll
    for (int o = 32; o > 0; o >>= 1) {
      agg += __shfl_down(agg, o);
      reg += __shfl_down(reg, o);
      dis += __shfl_down(dis, o);
      npair += __shfl_down(npair, o);
    }

    if (lane == 0) {
      const float l_agg = agg / fmaxf((float)(num_instance - 1), 1.0f);
      const float l_dis = (num_instance > 2) ? dis / fmaxf(npair, 1.0f) : 0.f;
      const float l_reg = reg / fmaxf((float)num_instance, 1.0f) * REG_W;
      const float loss = l_agg + l_dis + l_reg;
      out[b] = (num_instance <= 1) ? 0.f : loss;
    }
  }
}

extern "C" void kernel_launch(void* const* d_in, const int* in_sizes, int n_in,
                              void* d_out, int out_size, void* d_ws,
                              size_t ws_size, hipStream_t stream) {
  const float* emb = (const float*)d_in[0];
  const int* instance = (const int*)d_in[1];
  const float* kern = (const float*)d_in[2];
  const float* mask = (const float*)d_in[3];
  float* out = (float*)d_out;
  float* ws = (float*)d_ws;

  dim3 gridA(NBA, BATCH);  // 2120 blocks, 2 quads per thread
  kA<<<gridA, 256, 0, stream>>>(emb, instance, kern, mask, ws);
  dim3 gridB(48, BATCH);   // one wave per (batch, elem) column
  kB<<<gridB, 256, 0, stream>>>(ws);
  kC<<<gridA, 256, 0, stream>>>(ws);
  kD<<<BATCH, 1024, 0, stream>>>(ws, out);
}